// Round 3
// baseline (2927.970 us; speedup 1.0000x reference)
//
#include <hip/hip_runtime.h>
#include <hip/hip_bf16.h>

// ---------------------------------------------------------------------------
// 2-layer GCN, N=100000 nodes, E=3200000 edges, 128 -> 64 -> 64.
// out[i] = dinv[i] * ( sum_{e: dst=i} g[src_e] + g[i] ) + b,  g = (x@W)*dinv,
// dinv = rsqrt(indeg+1).
//
// CSR-free pipeline: edges are partitioned into buckets of BN=128 consecutive
// dst nodes (packed src | dloc<<17; requires N <= 2^17 = 131072). Aggregation
// processes one bucket per block, accumulating g[src] into a 32 KB LDS tile
// with workgroup-scope ds_add_f32. This avoids the 200 MB write-allocate
// traffic of a fully random CSR scatter (round-2 profile: 243 us, 197 MB
// writes) and all per-node global atomics.
// ---------------------------------------------------------------------------

#define BN 128          // nodes per bucket
#define CURPAD 16       // pad bucket cursors to 64B to spread L2 atomics

__global__ void k_init0(int* bcnt, int* flag, int nb) {
    int i = threadIdx.x + blockIdx.x * blockDim.x;
    if (i < nb) bcnt[i] = 0;
    if (i == 0) *flag = 0;
}

// Decide whether edge_index is stored as int32 or int64 words.
__global__ void k_detect(const int* ei, int* flag, long long E) {
    int t = blockIdx.x * blockDim.x + threadIdx.x;   // 1024 threads
    long long k = (long long)t * (E / 1024);
    if (k < E) {
        if (ei[2 * k + 1] != 0) atomicOr(flag, 1);   // 1 => int32 layout
    }
}

__device__ __forceinline__ int edge_at(const int* ei, int is32, long long idx) {
    return is32 ? ei[idx] : ei[2 * idx];
}

// Coarse histogram of dst>>7 with LDS staging (nb <= 1024).
__global__ __launch_bounds__(256) void k_hist(const int* ei, const int* flag,
                                              int* bcnt, long long E, int nb) {
    __shared__ int h[1024];
    for (int i = threadIdx.x; i < nb; i += blockDim.x) h[i] = 0;
    __syncthreads();
    int is32 = *flag;
    for (long long e = (long long)blockIdx.x * blockDim.x + threadIdx.x; e < E;
         e += (long long)gridDim.x * blockDim.x) {
        int d = edge_at(ei, is32, E + e);
        atomicAdd(&h[d >> 7], 1);
    }
    __syncthreads();
    for (int i = threadIdx.x; i < nb; i += blockDim.x)
        if (h[i]) atomicAdd(&bcnt[i], h[i]);
}

// Exclusive scan of bucket counts (nb <= 1024) -> bbase; init padded cursors.
__global__ __launch_bounds__(1024) void k_bscan(const int* bcnt, int* bbase,
                                                int* bcur, int nb) {
    __shared__ int s[1024];
    int t = threadIdx.x;
    int v = (t < nb) ? bcnt[t] : 0;
    s[t] = v;
    __syncthreads();
    for (int d = 1; d < 1024; d <<= 1) {
        int x = (t >= d) ? s[t - d] : 0;
        __syncthreads();
        s[t] += x;
        __syncthreads();
    }
    if (t < nb) {
        bbase[t] = s[t] - v;
        bcur[t * CURPAD] = s[t] - v;
        if (t == nb - 1) bbase[nb] = s[t];
    }
}

// Bucket the edges: packed = src | (dst&127)<<17. Writes advance ~nb
// L2-resident frontiers -> near-streaming write traffic.
__global__ __launch_bounds__(256) void k_bucket(const int* ei, const int* flag,
                                                int* bcur, int* bucketed,
                                                long long E) {
    long long e = (long long)blockIdx.x * blockDim.x + threadIdx.x;
    if (e >= E) return;
    int is32 = *flag;
    int s = edge_at(ei, is32, e);
    int d = edge_at(ei, is32, E + e);
    int pos = atomicAdd(&bcur[(d >> 7) * CURPAD], 1);
    bucketed[pos] = s | ((d & (BN - 1)) << 17);
}

// Per-bucket fine histogram (LDS) -> dinv = rsqrt(deg+1).
__global__ __launch_bounds__(256) void k_cnt_fine(const int* bucketed,
                                                  const int* bbase, float* dinv,
                                                  int n) {
    __shared__ int h[BN];
    if (threadIdx.x < BN) h[threadIdx.x] = 0;
    __syncthreads();
    int b = blockIdx.x;
    for (int e = bbase[b] + threadIdx.x; e < bbase[b + 1]; e += blockDim.x)
        atomicAdd(&h[bucketed[e] >> 17], 1);
    __syncthreads();
    int node = b * BN + threadIdx.x;
    if (threadIdx.x < BN && node < n)
        dinv[node] = rsqrtf((float)(h[threadIdx.x] + 1));
}

// ---------------------------------------------------------------------------
// Register-tiled GEMM: C[n x 64] = X[n x K_IN] * W[K_IN x 64], scaled by dinv.
// Block = 256 threads, tile = 64x64, thread = 4x4 micro-tile, BK=32.
// ---------------------------------------------------------------------------
template <int K_IN>
__global__ __launch_bounds__(256) void k_gemm2(const float* __restrict__ X,
                                               const float* __restrict__ W,
                                               const float* __restrict__ dinv,
                                               float* __restrict__ G, int n) {
    __shared__ float Xs[64][33];
    __shared__ float Ws[32][64];
    const int t = threadIdx.x;
    const int tx = t & 15;
    const int ty = t >> 4;
    const int r0 = blockIdx.x * 64;

    float acc[4][4] = {};

    for (int kb = 0; kb < K_IN; kb += 32) {
        {
            const int kq = t & 7;
            const int rr = t >> 3;
#pragma unroll
            for (int it = 0; it < 2; ++it) {
                int r = r0 + rr + it * 32;
                int rc = r < n ? r : n - 1;
                float4 xv = *(const float4*)(X + (size_t)rc * K_IN + kb + kq * 4);
                float* xd = &Xs[rr + it * 32][kq * 4];
                xd[0] = xv.x; xd[1] = xv.y; xd[2] = xv.z; xd[3] = xv.w;
            }
        }
        {
            const int cq = t & 15;
            const int kr = t >> 4;
#pragma unroll
            for (int it = 0; it < 2; ++it) {
                float4 wv = *(const float4*)(W + (size_t)(kb + kr + it * 16) * 64 + cq * 4);
                *(float4*)&Ws[kr + it * 16][cq * 4] = wv;
            }
        }
        __syncthreads();
#pragma unroll 8
        for (int k = 0; k < 32; ++k) {
            float4 wv = *(const float4*)&Ws[k][tx * 4];
            float x0 = Xs[ty * 4 + 0][k];
            float x1 = Xs[ty * 4 + 1][k];
            float x2 = Xs[ty * 4 + 2][k];
            float x3 = Xs[ty * 4 + 3][k];
            acc[0][0] = fmaf(x0, wv.x, acc[0][0]);
            acc[0][1] = fmaf(x0, wv.y, acc[0][1]);
            acc[0][2] = fmaf(x0, wv.z, acc[0][2]);
            acc[0][3] = fmaf(x0, wv.w, acc[0][3]);
            acc[1][0] = fmaf(x1, wv.x, acc[1][0]);
            acc[1][1] = fmaf(x1, wv.y, acc[1][1]);
            acc[1][2] = fmaf(x1, wv.z, acc[1][2]);
            acc[1][3] = fmaf(x1, wv.w, acc[1][3]);
            acc[2][0] = fmaf(x2, wv.x, acc[2][0]);
            acc[2][1] = fmaf(x2, wv.y, acc[2][1]);
            acc[2][2] = fmaf(x2, wv.z, acc[2][2]);
            acc[2][3] = fmaf(x2, wv.w, acc[2][3]);
            acc[3][0] = fmaf(x3, wv.x, acc[3][0]);
            acc[3][1] = fmaf(x3, wv.y, acc[3][1]);
            acc[3][2] = fmaf(x3, wv.z, acc[3][2]);
            acc[3][3] = fmaf(x3, wv.w, acc[3][3]);
        }
        __syncthreads();
    }
#pragma unroll
    for (int j = 0; j < 4; ++j) {
        int r = r0 + ty * 4 + j;
        if (r < n) {
            float dv = dinv[r];
            float4 o;
            o.x = acc[j][0] * dv;
            o.y = acc[j][1] * dv;
            o.z = acc[j][2] * dv;
            o.w = acc[j][3] * dv;
            *(float4*)(G + (size_t)r * 64 + tx * 4) = o;
        }
    }
}

// ---------------------------------------------------------------------------
// Bucketed aggregation: one block per bucket (BN nodes), LDS f32 accumulate.
// Wave w handles edges e0+w, e0+w+8, ... ; lane = feature dim.
// ---------------------------------------------------------------------------
template <bool RELU>
__global__ __launch_bounds__(512) void k_aggb(const float* __restrict__ G,
                                              const int* __restrict__ bucketed,
                                              const int* __restrict__ bbase,
                                              const float* __restrict__ dinv,
                                              const float* __restrict__ bias,
                                              float* __restrict__ OUT, int n) {
    __shared__ float accum[BN * 64];
    for (int i = threadIdx.x; i < BN * 64; i += 512) accum[i] = 0.f;
    __syncthreads();

    const int lane = threadIdx.x & 63;
    const int w = threadIdx.x >> 6;               // 0..7
    const int b = blockIdx.x;
    const int e0 = bbase[b], e1 = bbase[b + 1];
    const int ecnt = e1 - e0;

    int idx = w;
    for (; idx + 24 < ecnt; idx += 32) {          // 4 edges per wave per iter
        int pk0 = bucketed[e0 + idx];
        int pk1 = bucketed[e0 + idx + 8];
        int pk2 = bucketed[e0 + idx + 16];
        int pk3 = bucketed[e0 + idx + 24];
        float v0 = G[(size_t)(pk0 & 0x1FFFF) * 64 + lane];
        float v1 = G[(size_t)(pk1 & 0x1FFFF) * 64 + lane];
        float v2 = G[(size_t)(pk2 & 0x1FFFF) * 64 + lane];
        float v3 = G[(size_t)(pk3 & 0x1FFFF) * 64 + lane];
        __hip_atomic_fetch_add(&accum[(pk0 >> 17) * 64 + lane], v0,
                               __ATOMIC_RELAXED, __HIP_MEMORY_SCOPE_WORKGROUP);
        __hip_atomic_fetch_add(&accum[(pk1 >> 17) * 64 + lane], v1,
                               __ATOMIC_RELAXED, __HIP_MEMORY_SCOPE_WORKGROUP);
        __hip_atomic_fetch_add(&accum[(pk2 >> 17) * 64 + lane], v2,
                               __ATOMIC_RELAXED, __HIP_MEMORY_SCOPE_WORKGROUP);
        __hip_atomic_fetch_add(&accum[(pk3 >> 17) * 64 + lane], v3,
                               __ATOMIC_RELAXED, __HIP_MEMORY_SCOPE_WORKGROUP);
    }
    for (; idx < ecnt; idx += 8) {
        int pk = bucketed[e0 + idx];
        float v = G[(size_t)(pk & 0x1FFFF) * 64 + lane];
        __hip_atomic_fetch_add(&accum[(pk >> 17) * 64 + lane], v,
                               __ATOMIC_RELAXED, __HIP_MEMORY_SCOPE_WORKGROUP);
    }
    __syncthreads();

    for (int nd = w; nd < BN; nd += 8) {
        int node = b * BN + nd;
        if (node >= n) break;
        float a = accum[nd * 64 + lane] + G[(size_t)node * 64 + lane]; // self loop
        float r = dinv[node] * a + bias[lane];
        if (RELU) r = fmaxf(r, 0.f);
        OUT[(size_t)node * 64 + lane] = r;
    }
}

extern "C" void kernel_launch(void* const* d_in, const int* in_sizes, int n_in,
                              void* d_out, int out_size, void* d_ws, size_t ws_size,
                              hipStream_t stream) {
    const float* x = (const float*)d_in[0];
    const int* ei = (const int*)d_in[1];
    const float* W1 = (const float*)d_in[2];
    const float* b1 = (const float*)d_in[3];
    const float* W2 = (const float*)d_in[4];
    const float* b2 = (const float*)d_in[5];
    float* out = (float*)d_out;

    const int N = in_sizes[0] / 128;          // requires N <= 131072 (17-bit pack)
    const long long E = in_sizes[1] / 2;
    const int NB = (N + BN - 1) / BN;         // buckets (<= 1024)

    char* p = (char*)d_ws;
    size_t off = 0;
    auto take = [&](size_t bytes) -> void* {
        void* r = p + off;
        off += (bytes + 255) & ~(size_t)255;
        return r;
    };
    int* bcnt = (int*)take((size_t)NB * 4);
    int* bbase = (int*)take((size_t)(NB + 1) * 4);
    int* bcur = (int*)take((size_t)NB * CURPAD * 4);
    int* flag = (int*)take(4);
    float* dinv = (float*)take((size_t)N * 4);
    int* bucketed = (int*)take((size_t)E * 4);
    float* gbuf = (float*)take((size_t)N * 64 * 4);
    float* hbuf = (float*)take((size_t)N * 64 * 4);
    (void)ws_size; (void)n_in; (void)out_size;

    int nb_e = (int)((E + 255) / 256);

    k_init0<<<(NB + 255) / 256, 256, 0, stream>>>(bcnt, flag, NB);
    k_detect<<<4, 256, 0, stream>>>(ei, flag, E);
    k_hist<<<512, 256, 0, stream>>>(ei, flag, bcnt, E, NB);
    k_bscan<<<1, 1024, 0, stream>>>(bcnt, bbase, bcur, NB);
    k_bucket<<<nb_e, 256, 0, stream>>>(ei, flag, bcur, bucketed, E);
    k_cnt_fine<<<NB, 256, 0, stream>>>(bucketed, bbase, dinv, N);

    k_gemm2<128><<<(N + 63) / 64, 256, 0, stream>>>(x, W1, dinv, gbuf, N);
    k_aggb<true><<<NB, 512, 0, stream>>>(gbuf, bucketed, bbase, dinv, b1, hbuf, N);
    k_gemm2<64><<<(N + 63) / 64, 256, 0, stream>>>(hbuf, W2, dinv, gbuf, N);
    k_aggb<false><<<NB, 512, 0, stream>>>(gbuf, bucketed, bbase, dinv, b2, out, N);
}

// Round 4
// 490.988 us; speedup vs baseline: 5.9634x; 5.9634x over previous
//
#include <hip/hip_runtime.h>
#include <hip/hip_bf16.h>

// ---------------------------------------------------------------------------
// 2-layer GCN, N=100000 nodes, E=3200000 edges, 128 -> 64 -> 64.
// out[i] = dinv[i] * ( sum_{e: dst=i} g[src_e] + g[i] ) + b,  g = (x@W)*dinv,
// dinv = rsqrt(indeg+1).
//
// CSR build without random scatter: edges are partitioned into buckets of
// BN=128 consecutive dst nodes (packed src | dloc<<17; needs N <= 2^17), then
// a per-bucket LDS counting sort emits exact CSR into the bucket's contiguous
// window. Aggregation = wave-per-node register accumulate at full occupancy
// (round-3 lesson: the gather is latency-bound and needs ~100K concurrent
// waves; LDS-tile accumulation starved MLP and was 10x slower).
// ---------------------------------------------------------------------------

#define BN 128          // nodes per bucket
#define CURPAD 16       // pad bucket cursors to 64B to spread L2 atomics

__global__ void k_init0(int* bcnt, int* flag, int nb) {
    int i = threadIdx.x + blockIdx.x * blockDim.x;
    if (i < nb) bcnt[i] = 0;
    if (i == 0) *flag = 0;
}

// Decide whether edge_index is stored as int32 or int64 words.
__global__ void k_detect(const int* ei, int* flag, long long E) {
    int t = blockIdx.x * blockDim.x + threadIdx.x;   // 1024 threads
    long long k = (long long)t * (E / 1024);
    if (k < E) {
        if (ei[2 * k + 1] != 0) atomicOr(flag, 1);   // 1 => int32 layout
    }
}

__device__ __forceinline__ int edge_at(const int* ei, int is32, long long idx) {
    return is32 ? ei[idx] : ei[2 * idx];
}

// Coarse histogram of dst>>7 with LDS staging (nb <= 1024).
__global__ __launch_bounds__(256) void k_hist(const int* ei, const int* flag,
                                              int* bcnt, long long E, int nb) {
    __shared__ int h[1024];
    for (int i = threadIdx.x; i < nb; i += blockDim.x) h[i] = 0;
    __syncthreads();
    int is32 = *flag;
    for (long long e = (long long)blockIdx.x * blockDim.x + threadIdx.x; e < E;
         e += (long long)gridDim.x * blockDim.x) {
        int d = edge_at(ei, is32, E + e);
        atomicAdd(&h[d >> 7], 1);
    }
    __syncthreads();
    for (int i = threadIdx.x; i < nb; i += blockDim.x)
        if (h[i]) atomicAdd(&bcnt[i], h[i]);
}

// Exclusive scan of bucket counts (nb <= 1024) -> bbase; init padded cursors.
__global__ __launch_bounds__(1024) void k_bscan(const int* bcnt, int* bbase,
                                                int* bcur, int* rowp, int nb,
                                                int n) {
    __shared__ int s[1024];
    int t = threadIdx.x;
    int v = (t < nb) ? bcnt[t] : 0;
    s[t] = v;
    __syncthreads();
    for (int d = 1; d < 1024; d <<= 1) {
        int x = (t >= d) ? s[t - d] : 0;
        __syncthreads();
        s[t] += x;
        __syncthreads();
    }
    if (t < nb) {
        bbase[t] = s[t] - v;
        bcur[t * CURPAD] = s[t] - v;
        if (t == nb - 1) { bbase[nb] = s[t]; rowp[n] = s[t]; }
    }
}

// Bucket the edges: packed = src | (dst&127)<<17. Writes advance ~nb
// L2-resident frontiers -> near-streaming write traffic.
__global__ __launch_bounds__(256) void k_bucket(const int* ei, const int* flag,
                                                int* bcur, int* bucketed,
                                                long long E) {
    long long e = (long long)blockIdx.x * blockDim.x + threadIdx.x;
    if (e >= E) return;
    int is32 = *flag;
    int s = edge_at(ei, is32, e);
    int d = edge_at(ei, is32, E + e);
    int pos = atomicAdd(&bcur[(d >> 7) * CURPAD], 1);
    bucketed[pos] = s | ((d & (BN - 1)) << 17);
}

// Per-bucket counting sort -> exact CSR (esrc ordered by dst) + rowp + dinv.
// All esrc writes land in the bucket's contiguous window [e0, e1): L2-local.
__global__ __launch_bounds__(256) void k_sortcsr(const int* __restrict__ bucketed,
                                                 const int* __restrict__ bbase,
                                                 int* __restrict__ esrc,
                                                 int* __restrict__ rowp,
                                                 float* __restrict__ dinv, int n) {
    __shared__ int h[BN];      // per-dloc counts (kept)
    __shared__ int tmp[BN];    // inclusive scan
    __shared__ int cur[BN];    // running cursors
    const int b = blockIdx.x;
    const int t = threadIdx.x;
    if (t < BN) h[t] = 0;
    __syncthreads();
    const int e0 = bbase[b], e1 = bbase[b + 1];
    for (int e = e0 + t; e < e1; e += 256)
        atomicAdd(&h[bucketed[e] >> 17], 1);
    __syncthreads();
    int v = (t < BN) ? h[t] : 0;
    if (t < BN) tmp[t] = v;
    __syncthreads();
    for (int d = 1; d < BN; d <<= 1) {
        int x = (t < BN && t >= d) ? tmp[t - d] : 0;
        __syncthreads();
        if (t < BN) tmp[t] += x;
        __syncthreads();
    }
    if (t < BN) {
        cur[t] = 0;
        int node = b * BN + t;
        if (node < n) {
            rowp[node] = e0 + tmp[t] - v;          // exclusive scan
            dinv[node] = rsqrtf((float)(v + 1));   // +1 self loop
        }
    }
    __syncthreads();
    for (int e = e0 + t; e < e1; e += 256) {
        int pk = bucketed[e];
        int dloc = pk >> 17;
        int pos = atomicAdd(&cur[dloc], 1);
        esrc[e0 + (tmp[dloc] - h[dloc]) + pos] = pk & 0x1FFFF;
    }
}

// ---------------------------------------------------------------------------
// Register-tiled GEMM: C[n x 64] = X[n x K_IN] * W[K_IN x 64], scaled by dinv.
// Block = 256 threads, tile = 64x64, thread = 4x4 micro-tile, BK=32.
// ---------------------------------------------------------------------------
template <int K_IN>
__global__ __launch_bounds__(256) void k_gemm2(const float* __restrict__ X,
                                               const float* __restrict__ W,
                                               const float* __restrict__ dinv,
                                               float* __restrict__ G, int n) {
    __shared__ float Xs[64][33];
    __shared__ float Ws[32][64];
    const int t = threadIdx.x;
    const int tx = t & 15;
    const int ty = t >> 4;
    const int r0 = blockIdx.x * 64;

    float acc[4][4] = {};

    for (int kb = 0; kb < K_IN; kb += 32) {
        {
            const int kq = t & 7;
            const int rr = t >> 3;
#pragma unroll
            for (int it = 0; it < 2; ++it) {
                int r = r0 + rr + it * 32;
                int rc = r < n ? r : n - 1;
                float4 xv = *(const float4*)(X + (size_t)rc * K_IN + kb + kq * 4);
                float* xd = &Xs[rr + it * 32][kq * 4];
                xd[0] = xv.x; xd[1] = xv.y; xd[2] = xv.z; xd[3] = xv.w;
            }
        }
        {
            const int cq = t & 15;
            const int kr = t >> 4;
#pragma unroll
            for (int it = 0; it < 2; ++it) {
                float4 wv = *(const float4*)(W + (size_t)(kb + kr + it * 16) * 64 + cq * 4);
                *(float4*)&Ws[kr + it * 16][cq * 4] = wv;
            }
        }
        __syncthreads();
#pragma unroll 8
        for (int k = 0; k < 32; ++k) {
            float4 wv = *(const float4*)&Ws[k][tx * 4];
            float x0 = Xs[ty * 4 + 0][k];
            float x1 = Xs[ty * 4 + 1][k];
            float x2 = Xs[ty * 4 + 2][k];
            float x3 = Xs[ty * 4 + 3][k];
            acc[0][0] = fmaf(x0, wv.x, acc[0][0]);
            acc[0][1] = fmaf(x0, wv.y, acc[0][1]);
            acc[0][2] = fmaf(x0, wv.z, acc[0][2]);
            acc[0][3] = fmaf(x0, wv.w, acc[0][3]);
            acc[1][0] = fmaf(x1, wv.x, acc[1][0]);
            acc[1][1] = fmaf(x1, wv.y, acc[1][1]);
            acc[1][2] = fmaf(x1, wv.z, acc[1][2]);
            acc[1][3] = fmaf(x1, wv.w, acc[1][3]);
            acc[2][0] = fmaf(x2, wv.x, acc[2][0]);
            acc[2][1] = fmaf(x2, wv.y, acc[2][1]);
            acc[2][2] = fmaf(x2, wv.z, acc[2][2]);
            acc[2][3] = fmaf(x2, wv.w, acc[2][3]);
            acc[3][0] = fmaf(x3, wv.x, acc[3][0]);
            acc[3][1] = fmaf(x3, wv.y, acc[3][1]);
            acc[3][2] = fmaf(x3, wv.z, acc[3][2]);
            acc[3][3] = fmaf(x3, wv.w, acc[3][3]);
        }
        __syncthreads();
    }
#pragma unroll
    for (int j = 0; j < 4; ++j) {
        int r = r0 + ty * 4 + j;
        if (r < n) {
            float dv = dinv[r];
            float4 o;
            o.x = acc[j][0] * dv;
            o.y = acc[j][1] * dv;
            o.z = acc[j][2] * dv;
            o.w = acc[j][3] * dv;
            *(float4*)(G + (size_t)r * 64 + tx * 4) = o;
        }
    }
}

// wave per node: coalesced 256B gathers of g[src], register accumulate.
// 0 LDS / 12 VGPR -> full occupancy; unroll-8 keeps 8 gathers in flight.
template <bool RELU>
__global__ __launch_bounds__(256) void k_agg(const float* __restrict__ G,
                                             const int* __restrict__ rowp,
                                             const int* __restrict__ esrc,
                                             const float* __restrict__ dinv,
                                             const float* __restrict__ bias,
                                             float* __restrict__ OUT, int n) {
    int lane = threadIdx.x & 63;
    int i = blockIdx.x * (blockDim.x >> 6) + (threadIdx.x >> 6);
    if (i >= n) return;
    float acc = G[(size_t)i * 64 + lane];              // self loop
    int e = rowp[i], e1 = rowp[i + 1];
    for (; e + 8 <= e1; e += 8) {
        int s0 = esrc[e], s1 = esrc[e + 1], s2 = esrc[e + 2], s3 = esrc[e + 3];
        int s4 = esrc[e + 4], s5 = esrc[e + 5], s6 = esrc[e + 6], s7 = esrc[e + 7];
        float a0 = G[(size_t)s0 * 64 + lane];
        float a1 = G[(size_t)s1 * 64 + lane];
        float a2 = G[(size_t)s2 * 64 + lane];
        float a3 = G[(size_t)s3 * 64 + lane];
        float a4 = G[(size_t)s4 * 64 + lane];
        float a5 = G[(size_t)s5 * 64 + lane];
        float a6 = G[(size_t)s6 * 64 + lane];
        float a7 = G[(size_t)s7 * 64 + lane];
        acc += a0 + a1 + a2 + a3 + a4 + a5 + a6 + a7;
    }
    for (; e < e1; ++e) acc += G[(size_t)esrc[e] * 64 + lane];
    float r = dinv[i] * acc + bias[lane];
    if (RELU) r = fmaxf(r, 0.f);
    OUT[(size_t)i * 64 + lane] = r;
}

extern "C" void kernel_launch(void* const* d_in, const int* in_sizes, int n_in,
                              void* d_out, int out_size, void* d_ws, size_t ws_size,
                              hipStream_t stream) {
    const float* x = (const float*)d_in[0];
    const int* ei = (const int*)d_in[1];
    const float* W1 = (const float*)d_in[2];
    const float* b1 = (const float*)d_in[3];
    const float* W2 = (const float*)d_in[4];
    const float* b2 = (const float*)d_in[5];
    float* out = (float*)d_out;

    const int N = in_sizes[0] / 128;          // requires N <= 131072 (17-bit pack)
    const long long E = in_sizes[1] / 2;
    const int NB = (N + BN - 1) / BN;         // buckets (<= 1024)

    char* p = (char*)d_ws;
    size_t off = 0;
    auto take = [&](size_t bytes) -> void* {
        void* r = p + off;
        off += (bytes + 255) & ~(size_t)255;
        return r;
    };
    int* bcnt = (int*)take((size_t)NB * 4);
    int* bbase = (int*)take((size_t)(NB + 1) * 4);
    int* bcur = (int*)take((size_t)NB * CURPAD * 4);
    int* flag = (int*)take(4);
    float* dinv = (float*)take((size_t)N * 4);
    int* rowp = (int*)take((size_t)(N + 1) * 4);
    int* bucketed = (int*)take((size_t)E * 4);
    int* esrc = (int*)take((size_t)E * 4);
    float* gbuf = (float*)take((size_t)N * 64 * 4);
    float* hbuf = (float*)take((size_t)N * 64 * 4);
    (void)ws_size; (void)n_in; (void)out_size;

    int nb_e = (int)((E + 255) / 256);

    k_init0<<<(NB + 255) / 256, 256, 0, stream>>>(bcnt, flag, NB);
    k_detect<<<4, 256, 0, stream>>>(ei, flag, E);
    k_hist<<<512, 256, 0, stream>>>(ei, flag, bcnt, E, NB);
    k_bscan<<<1, 1024, 0, stream>>>(bcnt, bbase, bcur, rowp, NB, N);
    k_bucket<<<nb_e, 256, 0, stream>>>(ei, flag, bcur, bucketed, E);
    k_sortcsr<<<NB, 256, 0, stream>>>(bucketed, bbase, esrc, rowp, dinv, N);

    k_gemm2<128><<<(N + 63) / 64, 256, 0, stream>>>(x, W1, dinv, gbuf, N);
    k_agg<true><<<(N + 3) / 4, 256, 0, stream>>>(gbuf, rowp, esrc, dinv, b1, hbuf, N);
    k_gemm2<64><<<(N + 63) / 64, 256, 0, stream>>>(hbuf, W2, dinv, gbuf, N);
    k_agg<false><<<(N + 3) / 4, 256, 0, stream>>>(gbuf, rowp, esrc, dinv, b2, out, N);
}

// Round 5
// 474.247 us; speedup vs baseline: 6.1739x; 1.0353x over previous
//
#include <hip/hip_runtime.h>
#include <hip/hip_bf16.h>

// ---------------------------------------------------------------------------
// 2-layer GCN, N=100000 nodes, E=3200000 edges, 128 -> 64 -> 64.
// out[i] = dinv[i] * ( sum_{e: dst=i} g[src_e] + g[i] ) + b,  g = (x@W)*dinv,
// dinv = rsqrt(indeg+1).
//
// CSR build without random scatter: edges are partitioned into buckets of
// BN=128 consecutive dst nodes (packed src | dloc<<17; needs N <= 2^17), then
// a per-bucket LDS counting sort emits exact CSR into the bucket's contiguous
// window. Aggregation = wave-per-node register accumulate at full occupancy.
//
// Round-4 lesson: a single write frontier per bucket is shared by blocks on
// all 8 XCDs -> the same 64B line lives dirty in 8 non-coherent L2s -> ~13x
// write amplification (162 MB for 12.8 MB payload). Fix: 8 sub-buckets per
// bucket keyed by (e>>8)&7 == blockIdx%8 of the writer in k_bucket, which
// de-facto round-robins across XCDs. Each frontier line is then written by
// one XCD only. Key is derivable from e alone, so the histogram pass computes
// identical bases and bucket windows stay contiguous (sub-buckets ordered
// inside each bucket) — downstream kernels unchanged.
// ---------------------------------------------------------------------------

#define BN 128          // nodes per bucket
#define NSUB 8          // XCD sub-buckets per bucket
#define CURPAD 16       // pad cursors to 64B to spread L2 atomics

__global__ void k_init0(int* bcnt, int* flag, int nb8) {
    int i = threadIdx.x + blockIdx.x * blockDim.x;
    if (i < nb8) bcnt[i] = 0;
    if (i == 0) *flag = 0;
}

// Decide whether edge_index is stored as int32 or int64 words.
__global__ void k_detect(const int* ei, int* flag, long long E) {
    int t = blockIdx.x * blockDim.x + threadIdx.x;   // 1024 threads
    long long k = (long long)t * (E / 1024);
    if (k < E) {
        if (ei[2 * k + 1] != 0) atomicOr(flag, 1);   // 1 => int32 layout
    }
}

__device__ __forceinline__ int edge_at(const int* ei, int is32, long long idx) {
    return is32 ? ei[idx] : ei[2 * idx];
}

// Histogram of (dst>>7, (e>>8)&7) with LDS staging (nb8 <= 8192).
__global__ __launch_bounds__(256) void k_hist(const int* ei, const int* flag,
                                              int* bcnt, long long E, int nb8) {
    __shared__ int h[8192];
    for (int i = threadIdx.x; i < nb8; i += 256) h[i] = 0;
    __syncthreads();
    int is32 = *flag;
    for (long long e = (long long)blockIdx.x * 256 + threadIdx.x; e < E;
         e += (long long)gridDim.x * 256) {
        int d = edge_at(ei, is32, E + e);
        int sub = (int)((e >> 8) & (NSUB - 1));      // writer block's XCD slot
        atomicAdd(&h[(d >> 7) * NSUB + sub], 1);
    }
    __syncthreads();
    for (int i = threadIdx.x; i < nb8; i += 256)
        if (h[i]) atomicAdd(&bcnt[i], h[i]);
}

// Exclusive scan of nb8 (<= 8192) sub-bucket counts -> bbase; init cursors.
__global__ __launch_bounds__(1024) void k_bscan(const int* bcnt, int* bbase,
                                                int* bcur, int* rowp, int nb8,
                                                int n) {
    __shared__ int s[1024];
    const int t = threadIdx.x;
    int loc[8];
    int sum = 0;
#pragma unroll
    for (int j = 0; j < 8; ++j) {
        int i = t * 8 + j;
        int v = (i < nb8) ? bcnt[i] : 0;
        loc[j] = sum;                 // exclusive within this thread's chunk
        sum += v;
    }
    s[t] = sum;
    __syncthreads();
    for (int d = 1; d < 1024; d <<= 1) {
        int x = (t >= d) ? s[t - d] : 0;
        __syncthreads();
        s[t] += x;
        __syncthreads();
    }
    int base = s[t] - sum;            // exclusive across threads
#pragma unroll
    for (int j = 0; j < 8; ++j) {
        int i = t * 8 + j;
        if (i < nb8) {
            bbase[i] = base + loc[j];
            bcur[i * CURPAD] = base + loc[j];
        }
    }
    if (t == 1023) { bbase[nb8] = s[t]; rowp[n] = s[t]; }
}

// Bucket the edges: packed = src | (dst&127)<<17, into XCD-local sub-bucket.
__global__ __launch_bounds__(256) void k_bucket(const int* ei, const int* flag,
                                                int* bcur, int* bucketed,
                                                long long E) {
    long long e = (long long)blockIdx.x * blockDim.x + threadIdx.x;
    if (e >= E) return;
    int is32 = *flag;
    int s = edge_at(ei, is32, e);
    int d = edge_at(ei, is32, E + e);
    int slot = (d >> 7) * NSUB + (blockIdx.x & (NSUB - 1));  // == (e>>8)&7
    int pos = atomicAdd(&bcur[slot * CURPAD], 1);
    bucketed[pos] = s | ((d & (BN - 1)) << 17);
}

// Per-bucket counting sort -> exact CSR (esrc ordered by dst) + rowp + dinv.
// All esrc writes land in the bucket's contiguous window [e0, e1): L2-local.
__global__ __launch_bounds__(256) void k_sortcsr(const int* __restrict__ bucketed,
                                                 const int* __restrict__ bbase,
                                                 int* __restrict__ esrc,
                                                 int* __restrict__ rowp,
                                                 float* __restrict__ dinv, int n) {
    __shared__ int h[BN];      // per-dloc counts (kept)
    __shared__ int tmp[BN];    // inclusive scan
    __shared__ int cur[BN];    // running cursors
    const int b = blockIdx.x;
    const int t = threadIdx.x;
    if (t < BN) h[t] = 0;
    __syncthreads();
    const int e0 = bbase[b * NSUB], e1 = bbase[b * NSUB + NSUB];
    for (int e = e0 + t; e < e1; e += 256)
        atomicAdd(&h[bucketed[e] >> 17], 1);
    __syncthreads();
    int v = (t < BN) ? h[t] : 0;
    if (t < BN) tmp[t] = v;
    __syncthreads();
    for (int d = 1; d < BN; d <<= 1) {
        int x = (t < BN && t >= d) ? tmp[t - d] : 0;
        __syncthreads();
        if (t < BN) tmp[t] += x;
        __syncthreads();
    }
    if (t < BN) {
        cur[t] = 0;
        int node = b * BN + t;
        if (node < n) {
            rowp[node] = e0 + tmp[t] - v;          // exclusive scan
            dinv[node] = rsqrtf((float)(v + 1));   // +1 self loop
        }
    }
    __syncthreads();
    for (int e = e0 + t; e < e1; e += 256) {
        int pk = bucketed[e];
        int dloc = pk >> 17;
        int pos = atomicAdd(&cur[dloc], 1);
        esrc[e0 + (tmp[dloc] - h[dloc]) + pos] = pk & 0x1FFFF;
    }
}

// ---------------------------------------------------------------------------
// Register-tiled GEMM: C[n x 64] = X[n x K_IN] * W[K_IN x 64], scaled by dinv.
// Block = 256 threads, tile = 64x64, thread = 4x4 micro-tile, BK=32.
// ---------------------------------------------------------------------------
template <int K_IN>
__global__ __launch_bounds__(256) void k_gemm2(const float* __restrict__ X,
                                               const float* __restrict__ W,
                                               const float* __restrict__ dinv,
                                               float* __restrict__ G, int n) {
    __shared__ float Xs[64][33];
    __shared__ float Ws[32][64];
    const int t = threadIdx.x;
    const int tx = t & 15;
    const int ty = t >> 4;
    const int r0 = blockIdx.x * 64;

    float acc[4][4] = {};

    for (int kb = 0; kb < K_IN; kb += 32) {
        {
            const int kq = t & 7;
            const int rr = t >> 3;
#pragma unroll
            for (int it = 0; it < 2; ++it) {
                int r = r0 + rr + it * 32;
                int rc = r < n ? r : n - 1;
                float4 xv = *(const float4*)(X + (size_t)rc * K_IN + kb + kq * 4);
                float* xd = &Xs[rr + it * 32][kq * 4];
                xd[0] = xv.x; xd[1] = xv.y; xd[2] = xv.z; xd[3] = xv.w;
            }
        }
        {
            const int cq = t & 15;
            const int kr = t >> 4;
#pragma unroll
            for (int it = 0; it < 2; ++it) {
                float4 wv = *(const float4*)(W + (size_t)(kb + kr + it * 16) * 64 + cq * 4);
                *(float4*)&Ws[kr + it * 16][cq * 4] = wv;
            }
        }
        __syncthreads();
#pragma unroll 8
        for (int k = 0; k < 32; ++k) {
            float4 wv = *(const float4*)&Ws[k][tx * 4];
            float x0 = Xs[ty * 4 + 0][k];
            float x1 = Xs[ty * 4 + 1][k];
            float x2 = Xs[ty * 4 + 2][k];
            float x3 = Xs[ty * 4 + 3][k];
            acc[0][0] = fmaf(x0, wv.x, acc[0][0]);
            acc[0][1] = fmaf(x0, wv.y, acc[0][1]);
            acc[0][2] = fmaf(x0, wv.z, acc[0][2]);
            acc[0][3] = fmaf(x0, wv.w, acc[0][3]);
            acc[1][0] = fmaf(x1, wv.x, acc[1][0]);
            acc[1][1] = fmaf(x1, wv.y, acc[1][1]);
            acc[1][2] = fmaf(x1, wv.z, acc[1][2]);
            acc[1][3] = fmaf(x1, wv.w, acc[1][3]);
            acc[2][0] = fmaf(x2, wv.x, acc[2][0]);
            acc[2][1] = fmaf(x2, wv.y, acc[2][1]);
            acc[2][2] = fmaf(x2, wv.z, acc[2][2]);
            acc[2][3] = fmaf(x2, wv.w, acc[2][3]);
            acc[3][0] = fmaf(x3, wv.x, acc[3][0]);
            acc[3][1] = fmaf(x3, wv.y, acc[3][1]);
            acc[3][2] = fmaf(x3, wv.z, acc[3][2]);
            acc[3][3] = fmaf(x3, wv.w, acc[3][3]);
        }
        __syncthreads();
    }
#pragma unroll
    for (int j = 0; j < 4; ++j) {
        int r = r0 + ty * 4 + j;
        if (r < n) {
            float dv = dinv[r];
            float4 o;
            o.x = acc[j][0] * dv;
            o.y = acc[j][1] * dv;
            o.z = acc[j][2] * dv;
            o.w = acc[j][3] * dv;
            *(float4*)(G + (size_t)r * 64 + tx * 4) = o;
        }
    }
}

// wave per node: coalesced 256B gathers of g[src], register accumulate.
// 0 LDS / 12 VGPR -> full occupancy; unroll-8 keeps 8 gathers in flight.
template <bool RELU>
__global__ __launch_bounds__(256) void k_agg(const float* __restrict__ G,
                                             const int* __restrict__ rowp,
                                             const int* __restrict__ esrc,
                                             const float* __restrict__ dinv,
                                             const float* __restrict__ bias,
                                             float* __restrict__ OUT, int n) {
    int lane = threadIdx.x & 63;
    int i = blockIdx.x * (blockDim.x >> 6) + (threadIdx.x >> 6);
    if (i >= n) return;
    float acc = G[(size_t)i * 64 + lane];              // self loop
    int e = rowp[i], e1 = rowp[i + 1];
    for (; e + 8 <= e1; e += 8) {
        int s0 = esrc[e], s1 = esrc[e + 1], s2 = esrc[e + 2], s3 = esrc[e + 3];
        int s4 = esrc[e + 4], s5 = esrc[e + 5], s6 = esrc[e + 6], s7 = esrc[e + 7];
        float a0 = G[(size_t)s0 * 64 + lane];
        float a1 = G[(size_t)s1 * 64 + lane];
        float a2 = G[(size_t)s2 * 64 + lane];
        float a3 = G[(size_t)s3 * 64 + lane];
        float a4 = G[(size_t)s4 * 64 + lane];
        float a5 = G[(size_t)s5 * 64 + lane];
        float a6 = G[(size_t)s6 * 64 + lane];
        float a7 = G[(size_t)s7 * 64 + lane];
        acc += a0 + a1 + a2 + a3 + a4 + a5 + a6 + a7;
    }
    for (; e < e1; ++e) acc += G[(size_t)esrc[e] * 64 + lane];
    float r = dinv[i] * acc + bias[lane];
    if (RELU) r = fmaxf(r, 0.f);
    OUT[(size_t)i * 64 + lane] = r;
}

extern "C" void kernel_launch(void* const* d_in, const int* in_sizes, int n_in,
                              void* d_out, int out_size, void* d_ws, size_t ws_size,
                              hipStream_t stream) {
    const float* x = (const float*)d_in[0];
    const int* ei = (const int*)d_in[1];
    const float* W1 = (const float*)d_in[2];
    const float* b1 = (const float*)d_in[3];
    const float* W2 = (const float*)d_in[4];
    const float* b2 = (const float*)d_in[5];
    float* out = (float*)d_out;

    const int N = in_sizes[0] / 128;          // requires N <= 131072 (17-bit pack)
    const long long E = in_sizes[1] / 2;
    const int NB = (N + BN - 1) / BN;         // buckets (<= 1024)
    const int NB8 = NB * NSUB;                // sub-buckets (<= 8192)

    char* p = (char*)d_ws;
    size_t off = 0;
    auto take = [&](size_t bytes) -> void* {
        void* r = p + off;
        off += (bytes + 255) & ~(size_t)255;
        return r;
    };
    int* bcnt = (int*)take((size_t)NB8 * 4);
    int* bbase = (int*)take((size_t)(NB8 + 1) * 4);
    int* bcur = (int*)take((size_t)NB8 * CURPAD * 4);
    int* flag = (int*)take(4);
    float* dinv = (float*)take((size_t)N * 4);
    int* rowp = (int*)take((size_t)(N + 1) * 4);
    int* bucketed = (int*)take((size_t)E * 4);
    int* esrc = (int*)take((size_t)E * 4);
    float* gbuf = (float*)take((size_t)N * 64 * 4);
    float* hbuf = (float*)take((size_t)N * 64 * 4);
    (void)ws_size; (void)n_in; (void)out_size;

    int nb_e = (int)((E + 255) / 256);

    k_init0<<<(NB8 + 255) / 256, 256, 0, stream>>>(bcnt, flag, NB8);
    k_detect<<<4, 256, 0, stream>>>(ei, flag, E);
    k_hist<<<128, 256, 0, stream>>>(ei, flag, bcnt, E, NB8);
    k_bscan<<<1, 1024, 0, stream>>>(bcnt, bbase, bcur, rowp, NB8, N);
    k_bucket<<<nb_e, 256, 0, stream>>>(ei, flag, bcur, bucketed, E);
    k_sortcsr<<<NB, 256, 0, stream>>>(bucketed, bbase, esrc, rowp, dinv, N);

    k_gemm2<128><<<(N + 63) / 64, 256, 0, stream>>>(x, W1, dinv, gbuf, N);
    k_agg<true><<<(N + 3) / 4, 256, 0, stream>>>(gbuf, rowp, esrc, dinv, b1, hbuf, N);
    k_gemm2<64><<<(N + 63) / 64, 256, 0, stream>>>(hbuf, W2, dinv, gbuf, N);
    k_agg<false><<<(N + 3) / 4, 256, 0, stream>>>(gbuf, rowp, esrc, dinv, b2, out, N);
}

// Round 6
// 371.996 us; speedup vs baseline: 7.8710x; 1.2749x over previous
//
#include <hip/hip_runtime.h>
#include <hip/hip_bf16.h>

// ---------------------------------------------------------------------------
// 2-layer GCN, N=100000 nodes, E=3200000 edges, 128 -> 64 -> 64.
// out[i] = dinv[i] * ( sum_{e: dst=i} g[src_e] + g[i] ) + b,  g = (x@W)*dinv,
// dinv = rsqrt(indeg+1).
//
// Round-5 lesson: any single-cursor scatter (even XCD-keyed) suffers ~9x
// write amplification: frontier lines are evicted between partial fills and
// 3.2M device atomics ride the fabric. This version builds CSR with ZERO
// global atomics and ~1x write amplification:
//   pass 1 (k_localsort): per-block LDS counting sort of a 4096-edge chunk by
//     coarse bucket (512 dst nodes); sorted chunk dumped sequentially into the
//     block's private region (fully coalesced), plus per-chunk bin offsets.
//   k_colsum/k_cscan: per-coarse-bucket totals and global bases.
//   pass 2 (k_fine): one block per coarse bucket gathers its segments from all
//     chunks (L2/L3-resident reads), LDS-histograms 512 fine bins -> rowp/dinv,
//     then emits exact CSR; scattered writes stay inside the bucket's private
//     65KB window owned by a single block -> single L2, lines fill before
//     writeback.
// Aggregation = wave-per-node register accumulate at full occupancy
// (round-3 lesson: the random gather is latency-bound, needs ~100K waves).
// ---------------------------------------------------------------------------

#define CHUNK 4096      // edges per localsort block
#define CB    512       // nodes per coarse bucket (=> <=256 buckets, u8 keys)
#define NCMAX 1024      // max chunks supported by k_fine LDS

__global__ void k_initf(int* flag) { *flag = 0; }

// Decide whether edge_index is stored as int32 or int64 words.
__global__ void k_detect(const int* ei, int* flag, long long E) {
    int t = blockIdx.x * blockDim.x + threadIdx.x;   // 1024 threads
    long long k = (long long)t * (E / 1024);
    if (k < E) {
        if (ei[2 * k + 1] != 0) atomicOr(flag, 1);   // 1 => int32 layout
    }
}

__device__ __forceinline__ int edge_at(const int* ei, int is32, long long idx) {
    return is32 ? ei[idx] : ei[2 * idx];
}

// ---------------------------------------------------------------------------
// Pass 1: per-chunk LDS counting sort by coarse bucket (d >> 9).
// Output: sorted_all[chunk region] (coalesced), off_local[b][0..NC] exclusive
// bin offsets within the chunk (off_local[b][NC] = chunk size).
// ---------------------------------------------------------------------------
__global__ __launch_bounds__(256) void k_localsort(const int* __restrict__ ei,
                                                   const int* __restrict__ flag,
                                                   int* __restrict__ sorted_all,
                                                   int* __restrict__ off_local,
                                                   long long E, int NC) {
    __shared__ unsigned int  val[CHUNK];
    __shared__ unsigned char key[CHUNK];
    __shared__ unsigned int  srt[CHUNK];
    __shared__ int cnt[256], pos[256], cur[256];
    const int b = blockIdx.x;
    const int t = threadIdx.x;
    const long long base = (long long)b * CHUNK;
    const int nE = (int)((E - base < CHUNK) ? (E - base) : CHUNK);
    const int is32 = *flag;

    for (int i = t; i < nE; i += 256) {
        int s = edge_at(ei, is32, base + i);
        int d = edge_at(ei, is32, E + base + i);
        val[i] = (unsigned)s | ((unsigned)(d & (CB - 1)) << 17);
        key[i] = (unsigned char)(d >> 9);
    }
    cnt[t] = 0;
    __syncthreads();
    for (int i = t; i < nE; i += 256) atomicAdd(&cnt[key[i]], 1);
    __syncthreads();
    pos[t] = cnt[t];
    __syncthreads();
    for (int d = 1; d < 256; d <<= 1) {
        int x = (t >= d) ? pos[t - d] : 0;
        __syncthreads();
        pos[t] += x;
        __syncthreads();
    }
    cur[t] = pos[t] - cnt[t];                       // exclusive offset
    if (t < NC) off_local[b * (NC + 1) + t] = pos[t] - cnt[t];
    if (t == 0) off_local[b * (NC + 1) + NC] = nE;
    __syncthreads();
    for (int i = t; i < nE; i += 256) {
        int k = key[i];
        int p = atomicAdd(&cur[k], 1);
        srt[p] = val[i];
    }
    __syncthreads();
    for (int i = t; i < nE; i += 256) sorted_all[base + i] = (int)srt[i];
}

// Per-coarse-bucket totals: column sums of the off-diff matrix.
__global__ __launch_bounds__(256) void k_colsum(const int* __restrict__ off_local,
                                                int* __restrict__ totals,
                                                int nchunk, int NC) {
    __shared__ int s[256];
    const int c = blockIdx.x;
    const int t = threadIdx.x;
    int sum = 0;
    for (int b = t; b < nchunk; b += 256) {
        int rb = b * (NC + 1);
        sum += off_local[rb + c + 1] - off_local[rb + c];
    }
    s[t] = sum;
    __syncthreads();
    for (int d = 128; d > 0; d >>= 1) {
        if (t < d) s[t] += s[t + d];
        __syncthreads();
    }
    if (t == 0) totals[c] = s[0];
}

// Exclusive scan of totals (NC <= 256) -> cbase; also rowp[n] = E.
__global__ __launch_bounds__(256) void k_cscan(const int* __restrict__ totals,
                                               int* __restrict__ cbase,
                                               int* __restrict__ rowp,
                                               int NC, int n) {
    __shared__ int s[256];
    const int t = threadIdx.x;
    int v = (t < NC) ? totals[t] : 0;
    s[t] = v;
    __syncthreads();
    for (int d = 1; d < 256; d <<= 1) {
        int x = (t >= d) ? s[t - d] : 0;
        __syncthreads();
        s[t] += x;
        __syncthreads();
    }
    if (t < NC) cbase[t] = s[t] - v;
    if (t == NC - 1) { cbase[NC] = s[t]; rowp[n] = s[t]; }
}

// ---------------------------------------------------------------------------
// Pass 2: one block per coarse bucket. Gather segments from all chunks,
// fine counting sort over CB=512 dst bins -> exact CSR + rowp + dinv.
// ---------------------------------------------------------------------------
__global__ __launch_bounds__(512) void k_fine(const int* __restrict__ sorted_all,
                                              const int* __restrict__ off_local,
                                              const int* __restrict__ cbase,
                                              int* __restrict__ esrc,
                                              int* __restrict__ rowp,
                                              float* __restrict__ dinv,
                                              int nchunk, int NC, int n) {
    __shared__ int segoff[NCMAX];
    __shared__ int segend[NCMAX];
    __shared__ int hist[CB], incl[CB], cur[CB];
    const int c = blockIdx.x;
    const int t = threadIdx.x;
    for (int b = t; b < nchunk; b += 512) {
        int rb = b * (NC + 1);
        segoff[b] = b * CHUNK + off_local[rb + c];
        segend[b] = b * CHUNK + off_local[rb + c + 1];
    }
    hist[t] = 0;
    __syncthreads();
    for (int b = t; b < nchunk; b += 512)
        for (int i = segoff[b]; i < segend[b]; ++i)
            atomicAdd(&hist[((unsigned)sorted_all[i] >> 17) & (CB - 1)], 1);
    __syncthreads();
    incl[t] = hist[t];
    __syncthreads();
    for (int d = 1; d < 512; d <<= 1) {
        int x = (t >= d) ? incl[t - d] : 0;
        __syncthreads();
        incl[t] += x;
        __syncthreads();
    }
    const int base = cbase[c];
    cur[t] = base + incl[t] - hist[t];
    const int node = c * CB + t;
    if (node < n) {
        rowp[node] = base + incl[t] - hist[t];
        dinv[node] = rsqrtf((float)(hist[t] + 1));   // +1 self loop
    }
    __syncthreads();
    for (int b = t; b < nchunk; b += 512)
        for (int i = segoff[b]; i < segend[b]; ++i) {
            unsigned v = (unsigned)sorted_all[i];
            int dl = (v >> 17) & (CB - 1);
            int p = atomicAdd(&cur[dl], 1);
            esrc[p] = (int)(v & 0x1FFFF);
        }
}

// ---------------------------------------------------------------------------
// Register-tiled GEMM: C[n x 64] = X[n x K_IN] * W[K_IN x 64], scaled by dinv.
// Block = 256 threads, tile = 64x64, thread = 4x4 micro-tile, BK=32.
// ---------------------------------------------------------------------------
template <int K_IN>
__global__ __launch_bounds__(256) void k_gemm2(const float* __restrict__ X,
                                               const float* __restrict__ W,
                                               const float* __restrict__ dinv,
                                               float* __restrict__ G, int n) {
    __shared__ float Xs[64][33];
    __shared__ float Ws[32][64];
    const int t = threadIdx.x;
    const int tx = t & 15;
    const int ty = t >> 4;
    const int r0 = blockIdx.x * 64;

    float acc[4][4] = {};

    for (int kb = 0; kb < K_IN; kb += 32) {
        {
            const int kq = t & 7;
            const int rr = t >> 3;
#pragma unroll
            for (int it = 0; it < 2; ++it) {
                int r = r0 + rr + it * 32;
                int rc = r < n ? r : n - 1;
                float4 xv = *(const float4*)(X + (size_t)rc * K_IN + kb + kq * 4);
                float* xd = &Xs[rr + it * 32][kq * 4];
                xd[0] = xv.x; xd[1] = xv.y; xd[2] = xv.z; xd[3] = xv.w;
            }
        }
        {
            const int cq = t & 15;
            const int kr = t >> 4;
#pragma unroll
            for (int it = 0; it < 2; ++it) {
                float4 wv = *(const float4*)(W + (size_t)(kb + kr + it * 16) * 64 + cq * 4);
                *(float4*)&Ws[kr + it * 16][cq * 4] = wv;
            }
        }
        __syncthreads();
#pragma unroll 8
        for (int k = 0; k < 32; ++k) {
            float4 wv = *(const float4*)&Ws[k][tx * 4];
            float x0 = Xs[ty * 4 + 0][k];
            float x1 = Xs[ty * 4 + 1][k];
            float x2 = Xs[ty * 4 + 2][k];
            float x3 = Xs[ty * 4 + 3][k];
            acc[0][0] = fmaf(x0, wv.x, acc[0][0]);
            acc[0][1] = fmaf(x0, wv.y, acc[0][1]);
            acc[0][2] = fmaf(x0, wv.z, acc[0][2]);
            acc[0][3] = fmaf(x0, wv.w, acc[0][3]);
            acc[1][0] = fmaf(x1, wv.x, acc[1][0]);
            acc[1][1] = fmaf(x1, wv.y, acc[1][1]);
            acc[1][2] = fmaf(x1, wv.z, acc[1][2]);
            acc[1][3] = fmaf(x1, wv.w, acc[1][3]);
            acc[2][0] = fmaf(x2, wv.x, acc[2][0]);
            acc[2][1] = fmaf(x2, wv.y, acc[2][1]);
            acc[2][2] = fmaf(x2, wv.z, acc[2][2]);
            acc[2][3] = fmaf(x2, wv.w, acc[2][3]);
            acc[3][0] = fmaf(x3, wv.x, acc[3][0]);
            acc[3][1] = fmaf(x3, wv.y, acc[3][1]);
            acc[3][2] = fmaf(x3, wv.z, acc[3][2]);
            acc[3][3] = fmaf(x3, wv.w, acc[3][3]);
        }
        __syncthreads();
    }
#pragma unroll
    for (int j = 0; j < 4; ++j) {
        int r = r0 + ty * 4 + j;
        if (r < n) {
            float dv = dinv[r];
            float4 o;
            o.x = acc[j][0] * dv;
            o.y = acc[j][1] * dv;
            o.z = acc[j][2] * dv;
            o.w = acc[j][3] * dv;
            *(float4*)(G + (size_t)r * 64 + tx * 4) = o;
        }
    }
}

// wave per node: coalesced 256B gathers of g[src], register accumulate.
// 0 LDS / 12 VGPR -> full occupancy; unroll-8 keeps 8 gathers in flight.
template <bool RELU>
__global__ __launch_bounds__(256) void k_agg(const float* __restrict__ G,
                                             const int* __restrict__ rowp,
                                             const int* __restrict__ esrc,
                                             const float* __restrict__ dinv,
                                             const float* __restrict__ bias,
                                             float* __restrict__ OUT, int n) {
    int lane = threadIdx.x & 63;
    int i = blockIdx.x * (blockDim.x >> 6) + (threadIdx.x >> 6);
    if (i >= n) return;
    float acc = G[(size_t)i * 64 + lane];              // self loop
    int e = rowp[i], e1 = rowp[i + 1];
    for (; e + 8 <= e1; e += 8) {
        int s0 = esrc[e], s1 = esrc[e + 1], s2 = esrc[e + 2], s3 = esrc[e + 3];
        int s4 = esrc[e + 4], s5 = esrc[e + 5], s6 = esrc[e + 6], s7 = esrc[e + 7];
        float a0 = G[(size_t)s0 * 64 + lane];
        float a1 = G[(size_t)s1 * 64 + lane];
        float a2 = G[(size_t)s2 * 64 + lane];
        float a3 = G[(size_t)s3 * 64 + lane];
        float a4 = G[(size_t)s4 * 64 + lane];
        float a5 = G[(size_t)s5 * 64 + lane];
        float a6 = G[(size_t)s6 * 64 + lane];
        float a7 = G[(size_t)s7 * 64 + lane];
        acc += a0 + a1 + a2 + a3 + a4 + a5 + a6 + a7;
    }
    for (; e < e1; ++e) acc += G[(size_t)esrc[e] * 64 + lane];
    float r = dinv[i] * acc + bias[lane];
    if (RELU) r = fmaxf(r, 0.f);
    OUT[(size_t)i * 64 + lane] = r;
}

extern "C" void kernel_launch(void* const* d_in, const int* in_sizes, int n_in,
                              void* d_out, int out_size, void* d_ws, size_t ws_size,
                              hipStream_t stream) {
    const float* x = (const float*)d_in[0];
    const int* ei = (const int*)d_in[1];
    const float* W1 = (const float*)d_in[2];
    const float* b1 = (const float*)d_in[3];
    const float* W2 = (const float*)d_in[4];
    const float* b2 = (const float*)d_in[5];
    float* out = (float*)d_out;

    const int N = in_sizes[0] / 128;          // requires N <= 131072 (17-bit src)
    const long long E = in_sizes[1] / 2;
    const int NCHUNK = (int)((E + CHUNK - 1) / CHUNK);  // <= NCMAX
    const int NC = (N + CB - 1) / CB;                    // coarse buckets <= 256

    char* p = (char*)d_ws;
    size_t off = 0;
    auto take = [&](size_t bytes) -> void* {
        void* r = p + off;
        off += (bytes + 255) & ~(size_t)255;
        return r;
    };
    int* flag = (int*)take(4);
    int* off_local = (int*)take((size_t)NCHUNK * (NC + 1) * 4);
    int* totals = (int*)take((size_t)NC * 4);
    int* cbase = (int*)take((size_t)(NC + 1) * 4);
    int* rowp = (int*)take((size_t)(N + 1) * 4);
    float* dinv = (float*)take((size_t)N * 4);
    int* sorted_all = (int*)take((size_t)NCHUNK * CHUNK * 4);
    int* esrc = (int*)take((size_t)E * 4);
    float* gbuf = (float*)take((size_t)N * 64 * 4);
    float* hbuf = (float*)take((size_t)N * 64 * 4);
    (void)ws_size; (void)n_in; (void)out_size;

    k_initf<<<1, 1, 0, stream>>>(flag);
    k_detect<<<4, 256, 0, stream>>>(ei, flag, E);
    k_localsort<<<NCHUNK, 256, 0, stream>>>(ei, flag, sorted_all, off_local, E, NC);
    k_colsum<<<NC, 256, 0, stream>>>(off_local, totals, NCHUNK, NC);
    k_cscan<<<1, 256, 0, stream>>>(totals, cbase, rowp, NC, N);
    k_fine<<<NC, 512, 0, stream>>>(sorted_all, off_local, cbase, esrc, rowp, dinv,
                                   NCHUNK, NC, N);

    k_gemm2<128><<<(N + 63) / 64, 256, 0, stream>>>(x, W1, dinv, gbuf, N);
    k_agg<true><<<(N + 3) / 4, 256, 0, stream>>>(gbuf, rowp, esrc, dinv, b1, hbuf, N);
    k_gemm2<64><<<(N + 63) / 64, 256, 0, stream>>>(hbuf, W2, dinv, gbuf, N);
    k_agg<false><<<(N + 3) / 4, 256, 0, stream>>>(gbuf, rowp, esrc, dinv, b2, out, N);
}

// Round 7
// 325.822 us; speedup vs baseline: 8.9864x; 1.1417x over previous
//
#include <hip/hip_runtime.h>
#include <hip/hip_bf16.h>

// ---------------------------------------------------------------------------
// 2-layer GCN, N=100000 nodes, E=3200000 edges, 128 -> 64 -> 64.
// out[i] = dinv[i] * ( sum_{e: dst=i} g[src_e] + g[i] ) + b,  g = (x@W)*dinv,
// dinv = rsqrt(indeg+1).
//
// CSR build (round-6, kept): zero global atomics, ~1x write amplification.
//   k_localsort: per-block LDS counting sort of 4096-edge chunks by coarse
//     bucket (512 dst nodes), coalesced dump + per-chunk bin offsets.
//   k_colsum/k_cscan: per-coarse-bucket totals and global bases.
//   k_fine: one block per coarse bucket -> exact CSR + rowp + dinv, writes
//     confined to the bucket's private window (single L2).
//
// Round-7 change: G (the gather target) is stored in bf16. The aggregation is
// L2-miss-BW bound (round-6: FETCH 362MB vs 819MB demand, 3.2TB/s); bf16
// halves gather bytes and shrinks G to 12.8MB (~aggregate L2). Accumulation
// stays f32; hbuf / outputs / GEMM inputs stay f32. Error budget ~2-3e-3
// worst-case vs 6e-3 threshold.
// ---------------------------------------------------------------------------

#define CHUNK 4096      // edges per localsort block
#define CB    512       // nodes per coarse bucket (=> <=256 buckets, u8 keys)
#define NCMAX 1024      // max chunks supported by k_fine LDS

__device__ __forceinline__ unsigned short f2bf(float f) {
    union { float f; unsigned int u; } x; x.f = f;
    unsigned int r = (x.u + 0x7FFF + ((x.u >> 16) & 1)) >> 16;  // RNE
    return (unsigned short)r;
}
__device__ __forceinline__ float bf2f(unsigned short u) {
    union { unsigned int u; float f; } x; x.u = ((unsigned int)u) << 16;
    return x.f;
}

__global__ void k_initf(int* flag) { *flag = 0; }

// Decide whether edge_index is stored as int32 or int64 words.
__global__ void k_detect(const int* ei, int* flag, long long E) {
    int t = blockIdx.x * blockDim.x + threadIdx.x;   // 1024 threads
    long long k = (long long)t * (E / 1024);
    if (k < E) {
        if (ei[2 * k + 1] != 0) atomicOr(flag, 1);   // 1 => int32 layout
    }
}

__device__ __forceinline__ int edge_at(const int* ei, int is32, long long idx) {
    return is32 ? ei[idx] : ei[2 * idx];
}

// ---------------------------------------------------------------------------
// Pass 1: per-chunk LDS counting sort by coarse bucket (d >> 9).
// ---------------------------------------------------------------------------
__global__ __launch_bounds__(256) void k_localsort(const int* __restrict__ ei,
                                                   const int* __restrict__ flag,
                                                   int* __restrict__ sorted_all,
                                                   int* __restrict__ off_local,
                                                   long long E, int NC) {
    __shared__ unsigned int  val[CHUNK];
    __shared__ unsigned char key[CHUNK];
    __shared__ unsigned int  srt[CHUNK];
    __shared__ int cnt[256], pos[256], cur[256];
    const int b = blockIdx.x;
    const int t = threadIdx.x;
    const long long base = (long long)b * CHUNK;
    const int nE = (int)((E - base < CHUNK) ? (E - base) : CHUNK);
    const int is32 = *flag;

    for (int i = t; i < nE; i += 256) {
        int s = edge_at(ei, is32, base + i);
        int d = edge_at(ei, is32, E + base + i);
        val[i] = (unsigned)s | ((unsigned)(d & (CB - 1)) << 17);
        key[i] = (unsigned char)(d >> 9);
    }
    cnt[t] = 0;
    __syncthreads();
    for (int i = t; i < nE; i += 256) atomicAdd(&cnt[key[i]], 1);
    __syncthreads();
    pos[t] = cnt[t];
    __syncthreads();
    for (int d = 1; d < 256; d <<= 1) {
        int x = (t >= d) ? pos[t - d] : 0;
        __syncthreads();
        pos[t] += x;
        __syncthreads();
    }
    cur[t] = pos[t] - cnt[t];                       // exclusive offset
    if (t < NC) off_local[b * (NC + 1) + t] = pos[t] - cnt[t];
    if (t == 0) off_local[b * (NC + 1) + NC] = nE;
    __syncthreads();
    for (int i = t; i < nE; i += 256) {
        int k = key[i];
        int p = atomicAdd(&cur[k], 1);
        srt[p] = val[i];
    }
    __syncthreads();
    for (int i = t; i < nE; i += 256) sorted_all[base + i] = (int)srt[i];
}

// Per-coarse-bucket totals: column sums of the off-diff matrix.
__global__ __launch_bounds__(256) void k_colsum(const int* __restrict__ off_local,
                                                int* __restrict__ totals,
                                                int nchunk, int NC) {
    __shared__ int s[256];
    const int c = blockIdx.x;
    const int t = threadIdx.x;
    int sum = 0;
    for (int b = t; b < nchunk; b += 256) {
        int rb = b * (NC + 1);
        sum += off_local[rb + c + 1] - off_local[rb + c];
    }
    s[t] = sum;
    __syncthreads();
    for (int d = 128; d > 0; d >>= 1) {
        if (t < d) s[t] += s[t + d];
        __syncthreads();
    }
    if (t == 0) totals[c] = s[0];
}

// Exclusive scan of totals (NC <= 256) -> cbase; also rowp[n] = E.
__global__ __launch_bounds__(256) void k_cscan(const int* __restrict__ totals,
                                               int* __restrict__ cbase,
                                               int* __restrict__ rowp,
                                               int NC, int n) {
    __shared__ int s[256];
    const int t = threadIdx.x;
    int v = (t < NC) ? totals[t] : 0;
    s[t] = v;
    __syncthreads();
    for (int d = 1; d < 256; d <<= 1) {
        int x = (t >= d) ? s[t - d] : 0;
        __syncthreads();
        s[t] += x;
        __syncthreads();
    }
    if (t < NC) cbase[t] = s[t] - v;
    if (t == NC - 1) { cbase[NC] = s[t]; rowp[n] = s[t]; }
}

// ---------------------------------------------------------------------------
// Pass 2: one block per coarse bucket -> exact CSR + rowp + dinv.
// ---------------------------------------------------------------------------
__global__ __launch_bounds__(512) void k_fine(const int* __restrict__ sorted_all,
                                              const int* __restrict__ off_local,
                                              const int* __restrict__ cbase,
                                              int* __restrict__ esrc,
                                              int* __restrict__ rowp,
                                              float* __restrict__ dinv,
                                              int nchunk, int NC, int n) {
    __shared__ int segoff[NCMAX];
    __shared__ int segend[NCMAX];
    __shared__ int hist[CB], incl[CB], cur[CB];
    const int c = blockIdx.x;
    const int t = threadIdx.x;
    for (int b = t; b < nchunk; b += 512) {
        int rb = b * (NC + 1);
        segoff[b] = b * CHUNK + off_local[rb + c];
        segend[b] = b * CHUNK + off_local[rb + c + 1];
    }
    hist[t] = 0;
    __syncthreads();
    for (int b = t; b < nchunk; b += 512)
        for (int i = segoff[b]; i < segend[b]; ++i)
            atomicAdd(&hist[((unsigned)sorted_all[i] >> 17) & (CB - 1)], 1);
    __syncthreads();
    incl[t] = hist[t];
    __syncthreads();
    for (int d = 1; d < 512; d <<= 1) {
        int x = (t >= d) ? incl[t - d] : 0;
        __syncthreads();
        incl[t] += x;
        __syncthreads();
    }
    const int base = cbase[c];
    cur[t] = base + incl[t] - hist[t];
    const int node = c * CB + t;
    if (node < n) {
        rowp[node] = base + incl[t] - hist[t];
        dinv[node] = rsqrtf((float)(hist[t] + 1));   // +1 self loop
    }
    __syncthreads();
    for (int b = t; b < nchunk; b += 512)
        for (int i = segoff[b]; i < segend[b]; ++i) {
            unsigned v = (unsigned)sorted_all[i];
            int dl = (v >> 17) & (CB - 1);
            int p = atomicAdd(&cur[dl], 1);
            esrc[p] = (int)(v & 0x1FFFF);
        }
}

// ---------------------------------------------------------------------------
// Register-tiled GEMM: G[n x 64](bf16) = (X[n x K_IN] * W[K_IN x 64]) * dinv.
// Block = 256 threads, tile = 64x64, thread = 4x4 micro-tile, BK=32.
// ---------------------------------------------------------------------------
template <int K_IN>
__global__ __launch_bounds__(256) void k_gemm2(const float* __restrict__ X,
                                               const float* __restrict__ W,
                                               const float* __restrict__ dinv,
                                               unsigned short* __restrict__ G,
                                               int n) {
    __shared__ float Xs[64][33];
    __shared__ float Ws[32][64];
    const int t = threadIdx.x;
    const int tx = t & 15;
    const int ty = t >> 4;
    const int r0 = blockIdx.x * 64;

    float acc[4][4] = {};

    for (int kb = 0; kb < K_IN; kb += 32) {
        {
            const int kq = t & 7;
            const int rr = t >> 3;
#pragma unroll
            for (int it = 0; it < 2; ++it) {
                int r = r0 + rr + it * 32;
                int rc = r < n ? r : n - 1;
                float4 xv = *(const float4*)(X + (size_t)rc * K_IN + kb + kq * 4);
                float* xd = &Xs[rr + it * 32][kq * 4];
                xd[0] = xv.x; xd[1] = xv.y; xd[2] = xv.z; xd[3] = xv.w;
            }
        }
        {
            const int cq = t & 15;
            const int kr = t >> 4;
#pragma unroll
            for (int it = 0; it < 2; ++it) {
                float4 wv = *(const float4*)(W + (size_t)(kb + kr + it * 16) * 64 + cq * 4);
                *(float4*)&Ws[kr + it * 16][cq * 4] = wv;
            }
        }
        __syncthreads();
#pragma unroll 8
        for (int k = 0; k < 32; ++k) {
            float4 wv = *(const float4*)&Ws[k][tx * 4];
            float x0 = Xs[ty * 4 + 0][k];
            float x1 = Xs[ty * 4 + 1][k];
            float x2 = Xs[ty * 4 + 2][k];
            float x3 = Xs[ty * 4 + 3][k];
            acc[0][0] = fmaf(x0, wv.x, acc[0][0]);
            acc[0][1] = fmaf(x0, wv.y, acc[0][1]);
            acc[0][2] = fmaf(x0, wv.z, acc[0][2]);
            acc[0][3] = fmaf(x0, wv.w, acc[0][3]);
            acc[1][0] = fmaf(x1, wv.x, acc[1][0]);
            acc[1][1] = fmaf(x1, wv.y, acc[1][1]);
            acc[1][2] = fmaf(x1, wv.z, acc[1][2]);
            acc[1][3] = fmaf(x1, wv.w, acc[1][3]);
            acc[2][0] = fmaf(x2, wv.x, acc[2][0]);
            acc[2][1] = fmaf(x2, wv.y, acc[2][1]);
            acc[2][2] = fmaf(x2, wv.z, acc[2][2]);
            acc[2][3] = fmaf(x2, wv.w, acc[2][3]);
            acc[3][0] = fmaf(x3, wv.x, acc[3][0]);
            acc[3][1] = fmaf(x3, wv.y, acc[3][1]);
            acc[3][2] = fmaf(x3, wv.z, acc[3][2]);
            acc[3][3] = fmaf(x3, wv.w, acc[3][3]);
        }
        __syncthreads();
    }
#pragma unroll
    for (int j = 0; j < 4; ++j) {
        int r = r0 + ty * 4 + j;
        if (r < n) {
            float dv = dinv[r];
            union { unsigned short u[4]; uint2 v; } o;
            o.u[0] = f2bf(acc[j][0] * dv);
            o.u[1] = f2bf(acc[j][1] * dv);
            o.u[2] = f2bf(acc[j][2] * dv);
            o.u[3] = f2bf(acc[j][3] * dv);
            *(uint2*)(G + (size_t)r * 64 + tx * 4) = o.v;
        }
    }
}

// wave per node: coalesced 128B bf16 gathers of g[src], f32 register accum.
// 0 LDS, low VGPR -> full occupancy; unroll-8 keeps 8 gathers in flight.
template <bool RELU>
__global__ __launch_bounds__(256) void k_agg(const unsigned short* __restrict__ G,
                                             const int* __restrict__ rowp,
                                             const int* __restrict__ esrc,
                                             const float* __restrict__ dinv,
                                             const float* __restrict__ bias,
                                             float* __restrict__ OUT, int n) {
    int lane = threadIdx.x & 63;
    int i = blockIdx.x * (blockDim.x >> 6) + (threadIdx.x >> 6);
    if (i >= n) return;
    float acc = bf2f(G[(size_t)i * 64 + lane]);        // self loop
    int e = rowp[i], e1 = rowp[i + 1];
    for (; e + 8 <= e1; e += 8) {
        int s0 = esrc[e], s1 = esrc[e + 1], s2 = esrc[e + 2], s3 = esrc[e + 3];
        int s4 = esrc[e + 4], s5 = esrc[e + 5], s6 = esrc[e + 6], s7 = esrc[e + 7];
        unsigned short a0 = G[(size_t)s0 * 64 + lane];
        unsigned short a1 = G[(size_t)s1 * 64 + lane];
        unsigned short a2 = G[(size_t)s2 * 64 + lane];
        unsigned short a3 = G[(size_t)s3 * 64 + lane];
        unsigned short a4 = G[(size_t)s4 * 64 + lane];
        unsigned short a5 = G[(size_t)s5 * 64 + lane];
        unsigned short a6 = G[(size_t)s6 * 64 + lane];
        unsigned short a7 = G[(size_t)s7 * 64 + lane];
        acc += bf2f(a0) + bf2f(a1) + bf2f(a2) + bf2f(a3)
             + bf2f(a4) + bf2f(a5) + bf2f(a6) + bf2f(a7);
    }
    for (; e < e1; ++e) acc += bf2f(G[(size_t)esrc[e] * 64 + lane]);
    float r = dinv[i] * acc + bias[lane];
    if (RELU) r = fmaxf(r, 0.f);
    OUT[(size_t)i * 64 + lane] = r;
}

extern "C" void kernel_launch(void* const* d_in, const int* in_sizes, int n_in,
                              void* d_out, int out_size, void* d_ws, size_t ws_size,
                              hipStream_t stream) {
    const float* x = (const float*)d_in[0];
    const int* ei = (const int*)d_in[1];
    const float* W1 = (const float*)d_in[2];
    const float* b1 = (const float*)d_in[3];
    const float* W2 = (const float*)d_in[4];
    const float* b2 = (const float*)d_in[5];
    float* out = (float*)d_out;

    const int N = in_sizes[0] / 128;          // requires N <= 131072 (17-bit src)
    const long long E = in_sizes[1] / 2;
    const int NCHUNK = (int)((E + CHUNK - 1) / CHUNK);  // <= NCMAX
    const int NC = (N + CB - 1) / CB;                    // coarse buckets <= 256

    char* p = (char*)d_ws;
    size_t off = 0;
    auto take = [&](size_t bytes) -> void* {
        void* r = p + off;
        off += (bytes + 255) & ~(size_t)255;
        return r;
    };
    int* flag = (int*)take(4);
    int* off_local = (int*)take((size_t)NCHUNK * (NC + 1) * 4);
    int* totals = (int*)take((size_t)NC * 4);
    int* cbase = (int*)take((size_t)(NC + 1) * 4);
    int* rowp = (int*)take((size_t)(N + 1) * 4);
    float* dinv = (float*)take((size_t)N * 4);
    int* sorted_all = (int*)take((size_t)NCHUNK * CHUNK * 4);
    int* esrc = (int*)take((size_t)E * 4);
    unsigned short* gbuf = (unsigned short*)take((size_t)N * 64 * 2);
    float* hbuf = (float*)take((size_t)N * 64 * 4);
    (void)ws_size; (void)n_in; (void)out_size;

    k_initf<<<1, 1, 0, stream>>>(flag);
    k_detect<<<4, 256, 0, stream>>>(ei, flag, E);
    k_localsort<<<NCHUNK, 256, 0, stream>>>(ei, flag, sorted_all, off_local, E, NC);
    k_colsum<<<NC, 256, 0, stream>>>(off_local, totals, NCHUNK, NC);
    k_cscan<<<1, 256, 0, stream>>>(totals, cbase, rowp, NC, N);
    k_fine<<<NC, 512, 0, stream>>>(sorted_all, off_local, cbase, esrc, rowp, dinv,
                                   NCHUNK, NC, N);

    k_gemm2<128><<<(N + 63) / 64, 256, 0, stream>>>(x, W1, dinv, gbuf, N);
    k_agg<true><<<(N + 3) / 4, 256, 0, stream>>>(gbuf, rowp, esrc, dinv, b1, hbuf, N);
    k_gemm2<64><<<(N + 63) / 64, 256, 0, stream>>>(hbuf, W2, dinv, gbuf, N);
    k_agg<false><<<(N + 3) / 4, 256, 0, stream>>>(gbuf, rowp, esrc, dinv, b2, out, N);
}